// Round 3
// baseline (104.805 us; speedup 1.0000x reference)
//
#include <hip/hip_runtime.h>

#define G_ 20000
#define W_ 8
#define K_ 16
#define T_ 1500
#define B_ 256
#define D_ 2
#define GPB 2    // groups per 1-wave block -> grid 10000 x 4 = 40000 wave-blocks

typedef float v2f __attribute__((ext_vector_type(2)));

__device__ __forceinline__ float selu_f(float x) {
    const float scale = 1.0507009873554805f;
    const float sa    = 1.7580993408473766f;   // scale*alpha
    float e   = __expf(x);
    float neg = fmaf(sa, e, -sa);
    return x > 0.0f ? scale * x : neg;
}

// feat (B,T) -> featT (T,B): gather in main kernel becomes lane-coalesced.
__global__ void transpose_feat(const float* __restrict__ feat,
                               float* __restrict__ featT) {
    __shared__ float tile[32][33];
    int t0 = blockIdx.x * 32;
    int b0 = blockIdx.y * 32;
    int tx = threadIdx.x, ty = threadIdx.y;  // block (32,8)
    #pragma unroll
    for (int i = 0; i < 32; i += 8) {
        int bb = b0 + ty + i, tt = t0 + tx;
        if (bb < B_ && tt < T_) tile[ty + i][tx] = feat[bb * T_ + tt];
    }
    __syncthreads();
    #pragma unroll
    for (int i = 0; i < 32; i += 8) {
        int tt = t0 + ty + i, bb = b0 + tx;
        if (tt < T_ && bb < B_) featT[tt * B_ + bb] = tile[tx][ty + i];
    }
}

// Generic inner-2D transpose: in[o][a][bd] -> out[o][bd][a], writes coalesced.
__global__ void transpose_inner(const float* __restrict__ in,
                                float* __restrict__ out,
                                int A, int Bd, long n) {
    long i = (long)blockIdx.x * blockDim.x + threadIdx.x;
    if (i >= n) return;
    int  ab = A * Bd;
    long o  = i / ab;
    int  r  = (int)(i - o * ab);
    int  bd = r / A;
    int  a  = r - bd * A;
    out[i] = in[o * (long)ab + a * (long)Bd + bd];
}

// Fast path: transposed weights -> v_pk_fma_f32 packed over output dim.
// 1 wave per block, lane = batch element chunk, GPB consecutive groups.
__global__ __launch_bounds__(64, 8) void decoder_fast(
    const float* __restrict__ featT,   // (T,B)
    const int*   __restrict__ tf_idx,  // (G,K)
    const float* __restrict__ W1t,     // (G,K,W)   = W1 transposed
    const float* __restrict__ b1,      // (G,W)
    const float* __restrict__ Wmt,     // (D,G,W,W) = Wm with v/w swapped
    const float* __restrict__ bm,      // (D,G,W)
    const float* __restrict__ Wf,      // (G,W)
    const float* __restrict__ bf,      // (G,)
    float* __restrict__ out)           // (B,G)
{
    const int lane = threadIdx.x;
    const int b    = blockIdx.y * 64 + lane;
    const int g0   = blockIdx.x * GPB;
    const float* fb = featT + b;
    float res[GPB];

    #pragma unroll
    for (int gi = 0; gi < GPB; ++gi) {
        const int g = g0 + gi;

        // indices (uniform -> s_load_dwordx4) + coalesced gathers
        const int4* ip = (const int4*)(tf_idx + g * K_);
        int4 i0 = ip[0], i1 = ip[1], i2 = ip[2], i3 = ip[3];
        float xg[K_];
        xg[ 0]=fb[(size_t)i0.x*B_]; xg[ 1]=fb[(size_t)i0.y*B_];
        xg[ 2]=fb[(size_t)i0.z*B_]; xg[ 3]=fb[(size_t)i0.w*B_];
        xg[ 4]=fb[(size_t)i1.x*B_]; xg[ 5]=fb[(size_t)i1.y*B_];
        xg[ 6]=fb[(size_t)i1.z*B_]; xg[ 7]=fb[(size_t)i1.w*B_];
        xg[ 8]=fb[(size_t)i2.x*B_]; xg[ 9]=fb[(size_t)i2.y*B_];
        xg[10]=fb[(size_t)i2.z*B_]; xg[11]=fb[(size_t)i2.w*B_];
        xg[12]=fb[(size_t)i3.x*B_]; xg[13]=fb[(size_t)i3.y*B_];
        xg[14]=fb[(size_t)i3.z*B_]; xg[15]=fb[(size_t)i3.w*B_];

        // layer 1: acc pairs over output w; bias folded into init
        const v2f* wp = (const v2f*)(W1t + (size_t)g * (K_ * W_));
        const v2f* bp = (const v2f*)(b1  + (size_t)g * W_);
        v2f a0 = bp[0], a1 = bp[1], a2 = bp[2], a3 = bp[3];
        #pragma unroll
        for (int k = 0; k < K_; ++k) {
            float xk = xg[k];
            a0 += wp[4*k+0] * xk;
            a1 += wp[4*k+1] * xk;
            a2 += wp[4*k+2] * xk;
            a3 += wp[4*k+3] * xk;
        }
        float h[W_];
        h[0]=selu_f(a0.x); h[1]=selu_f(a0.y); h[2]=selu_f(a1.x); h[3]=selu_f(a1.y);
        h[4]=selu_f(a2.x); h[5]=selu_f(a2.y); h[6]=selu_f(a3.x); h[7]=selu_f(a3.y);

        // D mid layers: Wmt[d][g][w][v], acc pairs over output v
        #pragma unroll
        for (int d = 0; d < D_; ++d) {
            const v2f* wmp = (const v2f*)(Wmt + ((size_t)d * G_ + g) * (W_ * W_));
            const v2f* bmp = (const v2f*)(bm  + ((size_t)d * G_ + g) * W_);
            v2f m0 = bmp[0], m1 = bmp[1], m2 = bmp[2], m3 = bmp[3];
            #pragma unroll
            for (int w = 0; w < W_; ++w) {
                float hw = h[w];
                m0 += wmp[4*w+0] * hw;
                m1 += wmp[4*w+1] * hw;
                m2 += wmp[4*w+2] * hw;
                m3 += wmp[4*w+3] * hw;
            }
            h[0]=selu_f(m0.x); h[1]=selu_f(m0.y); h[2]=selu_f(m1.x); h[3]=selu_f(m1.y);
            h[4]=selu_f(m2.x); h[5]=selu_f(m2.y); h[6]=selu_f(m3.x); h[7]=selu_f(m3.y);
        }

        // final dot
        const float* wfp = Wf + (size_t)g * W_;
        float acc = bf[g];
        #pragma unroll
        for (int w = 0; w < W_; ++w) acc = fmaf(h[w], wfp[w], acc);
        res[gi] = acc;
    }

    // coalesced 8B store: (b*20000 + g0) even
    *(float2*)(out + (size_t)b * G_ + g0) = make_float2(res[0], res[1]);
}

// ---- fallback (round-2 path) if workspace too small for weight transposes ----
#define FGPB 4
template<bool TRANSPOSED>
__global__ __launch_bounds__(256) void decoder_kernel(
    const float* __restrict__ featsrc, const int* __restrict__ tf_idx,
    const float* __restrict__ W1, const float* __restrict__ b1,
    const float* __restrict__ Wm, const float* __restrict__ bm,
    const float* __restrict__ Wf, const float* __restrict__ bf,
    float* __restrict__ out)
{
    const int b  = threadIdx.x;
    const int g0 = blockIdx.x * FGPB;
    float res[FGPB];
    #pragma unroll
    for (int gi = 0; gi < FGPB; ++gi) {
        const int g = g0 + gi;
        float xg[K_];
        #pragma unroll
        for (int k = 0; k < K_; ++k) {
            int t = tf_idx[g * K_ + k];
            xg[k] = TRANSPOSED ? featsrc[t * B_ + b] : featsrc[b * T_ + t];
        }
        float h[W_];
        #pragma unroll
        for (int w = 0; w < W_; ++w) {
            float acc = b1[g * W_ + w];
            #pragma unroll
            for (int k = 0; k < K_; ++k)
                acc = fmaf(xg[k], W1[(g * W_ + w) * K_ + k], acc);
            h[w] = selu_f(acc);
        }
        #pragma unroll
        for (int d = 0; d < D_; ++d) {
            const float* wmd = Wm + ((size_t)d * G_ + g) * (W_ * W_);
            const float* bmd = bm + ((size_t)d * G_ + g) * W_;
            float h2[W_];
            #pragma unroll
            for (int v = 0; v < W_; ++v) {
                float acc = bmd[v];
                #pragma unroll
                for (int w = 0; w < W_; ++w)
                    acc = fmaf(h[w], wmd[v * W_ + w], acc);
                h2[v] = selu_f(acc);
            }
            #pragma unroll
            for (int w = 0; w < W_; ++w) h[w] = h2[w];
        }
        float acc = bf[g];
        #pragma unroll
        for (int w = 0; w < W_; ++w)
            acc = fmaf(h[w], Wf[g * W_ + w], acc);
        res[gi] = acc;
    }
    float4* o = (float4*)(out + (size_t)b * G_ + g0);
    o[0] = make_float4(res[0], res[1], res[2], res[3]);
}

extern "C" void kernel_launch(void* const* d_in, const int* in_sizes, int n_in,
                              void* d_out, int out_size, void* d_ws, size_t ws_size,
                              hipStream_t stream) {
    const float* feat   = (const float*)d_in[0];
    const int*   tf_idx = (const int*)  d_in[1];
    const float* W1     = (const float*)d_in[2];
    const float* b1     = (const float*)d_in[3];
    const float* Wm     = (const float*)d_in[4];
    const float* bm     = (const float*)d_in[5];
    const float* Wf     = (const float*)d_in[6];
    const float* bf     = (const float*)d_in[7];
    float* out = (float*)d_out;

    const size_t featT_b = (size_t)T_ * B_ * sizeof(float);            // 1.536 MB
    const size_t w1t_b   = (size_t)G_ * K_ * W_ * sizeof(float);       // 10.24 MB
    const size_t wmt_b   = (size_t)D_ * G_ * W_ * W_ * sizeof(float);  // 10.24 MB

    if (ws_size >= featT_b + w1t_b + wmt_b) {
        float* featT = (float*)d_ws;
        float* W1t   = (float*)((char*)d_ws + featT_b);
        float* Wmt   = (float*)((char*)d_ws + featT_b + w1t_b);

        dim3 tgrid((T_ + 31) / 32, (B_ + 31) / 32);
        hipLaunchKernelGGL(transpose_feat, tgrid, dim3(32, 8), 0, stream, feat, featT);

        long n1 = (long)G_ * W_ * K_;                 // 2,560,000
        hipLaunchKernelGGL(transpose_inner, dim3((n1 + 255) / 256), dim3(256), 0,
                           stream, W1, W1t, W_, K_, n1);
        long nm = (long)D_ * G_ * W_ * W_;            // 2,560,000
        hipLaunchKernelGGL(transpose_inner, dim3((nm + 255) / 256), dim3(256), 0,
                           stream, Wm, Wmt, W_, W_, nm);

        hipLaunchKernelGGL(decoder_fast, dim3(G_ / GPB, B_ / 64), dim3(64), 0,
                           stream, featT, tf_idx, W1t, b1, Wmt, bm, Wf, bf, out);
    } else if (ws_size >= featT_b) {
        float* featT = (float*)d_ws;
        dim3 tgrid((T_ + 31) / 32, (B_ + 31) / 32);
        hipLaunchKernelGGL(transpose_feat, tgrid, dim3(32, 8), 0, stream, feat, featT);
        hipLaunchKernelGGL((decoder_kernel<true>), dim3(G_ / FGPB), dim3(B_), 0,
                           stream, featT, tf_idx, W1, b1, Wm, bm, Wf, bf, out);
    } else {
        hipLaunchKernelGGL((decoder_kernel<false>), dim3(G_ / FGPB), dim3(B_), 0,
                           stream, feat, tf_idx, W1, b1, Wm, bm, Wf, bf, out);
    }
}

// Round 4
// 94.860 us; speedup vs baseline: 1.1048x; 1.1048x over previous
//
#include <hip/hip_runtime.h>

#define G_ 20000
#define W_ 8
#define K_ 16
#define T_ 1500
#define B_ 256
#define D_ 2
#define GPB 2        // groups per 256-thread block -> grid 10000, 40000 waves
#define PSTRIDE 292  // floats per packed group record (1168 B, 16B-aligned)

typedef float v2f __attribute__((ext_vector_type(2)));

// ---------- prep kernels ----------

// feat (B,T) -> featT (T,B): gather in main kernel becomes lane-coalesced.
__global__ void transpose_feat(const float* __restrict__ feat,
                               float* __restrict__ featT) {
    __shared__ float tile[32][33];
    int t0 = blockIdx.x * 32;
    int b0 = blockIdx.y * 32;
    int tx = threadIdx.x, ty = threadIdx.y;  // block (32,8)
    #pragma unroll
    for (int i = 0; i < 32; i += 8) {
        int bb = b0 + ty + i, tt = t0 + tx;
        if (bb < B_ && tt < T_) tile[ty + i][tx] = feat[bb * T_ + tt];
    }
    __syncthreads();
    #pragma unroll
    for (int i = 0; i < 32; i += 8) {
        int tt = t0 + ty + i, bb = b0 + tx;
        if (tt < T_ && bb < B_) featT[tt * B_ + bb] = tile[tx][ty + i];
    }
}

// Pack all per-group params into one contiguous record, transposed for
// pk_fma over the OUTPUT dim, with SELU constants folded in:
//   W1'  = log2e * W1^T        (layer-1 exp becomes bare v_exp_f32)
//   b1'  = log2e * b1
//   Wm'  = scale*log2e * Wm^T  (scale of previous SELU folded forward)
//   bm'  = log2e * bm
//   Wf'  = scale * Wf
// Layout (floats): [0,128) W1t[k][w]; [128,136) b1; [136,264) Wmt[d][w][v];
//                  [264,280) bm[d][v]; [280,288) Wf; [288] bf; [289,292) pad
__global__ void pack_weights(const float* __restrict__ W1,
                             const float* __restrict__ b1,
                             const float* __restrict__ Wm,
                             const float* __restrict__ bm,
                             const float* __restrict__ Wf,
                             const float* __restrict__ bf,
                             float* __restrict__ pack) {
    long i = (long)blockIdx.x * blockDim.x + threadIdx.x;
    if (i >= (long)G_ * PSTRIDE) return;
    int g = (int)(i / PSTRIDE);
    int j = (int)(i - (long)g * PSTRIDE);
    const float LOG2E = 1.44269504088896340736f;
    const float SCALE = 1.0507009873554805f;
    float v;
    if (j < 128) {
        int k = j >> 3, w = j & 7;
        v = LOG2E * W1[((long)g * W_ + w) * K_ + k];
    } else if (j < 136) {
        v = LOG2E * b1[g * W_ + (j - 128)];
    } else if (j < 264) {
        int r = j - 136, d = r >> 6, w = (r >> 3) & 7, vv = r & 7;
        v = SCALE * LOG2E * Wm[(((long)d * G_ + g) * W_ + vv) * W_ + w];
    } else if (j < 280) {
        int r = j - 264, d = r >> 3, vv = r & 7;
        v = LOG2E * bm[((long)d * G_ + g) * W_ + vv];
    } else if (j < 288) {
        v = SCALE * Wf[g * W_ + (j - 280)];
    } else if (j == 288) {
        v = bf[g];
    } else {
        v = 0.0f;
    }
    pack[i] = v;
}

// ---------- main kernel ----------

// input u = log2e * z ; returns selu(z)/scale  (scale folded into consumer)
__device__ __forceinline__ float selu_u(float u) {
    const float ALPHA = 1.6732632423543772f;
    const float LN2   = 0.6931471805599453f;
    float e   = __builtin_amdgcn_exp2f(u);      // single v_exp_f32
    float neg = fmaf(ALPHA, e, -ALPHA);
    return u > 0.0f ? u * LN2 : neg;
}

// One 256-thread block = GPB consecutive groups x all 256 batch rows.
// Weights fetched ONCE per group (uniform addr -> s_load broadcast).
__global__ __launch_bounds__(256, 8) void decoder_packed(
    const float* __restrict__ featT,   // (T,B)
    const int*   __restrict__ tf_idx,  // (G,K)
    const float* __restrict__ pack,    // (G,PSTRIDE)
    float* __restrict__ out)           // (B,G)
{
    const int b  = threadIdx.x;
    const int g0 = blockIdx.x * GPB;
    const float* fb = featT + b;
    float res[GPB];

    #pragma unroll
    for (int gi = 0; gi < GPB; ++gi) {
        const int g = g0 + gi;
        const float* P  = pack + (long)g * PSTRIDE;
        const v2f*   P2 = (const v2f*)P;

        // indices (uniform -> s_load) + coalesced per-lane gathers
        const int4* ip = (const int4*)(tf_idx + g * K_);
        int4 i0 = ip[0], i1 = ip[1], i2 = ip[2], i3 = ip[3];
        float xg[K_];
        xg[ 0]=fb[(size_t)i0.x*B_]; xg[ 1]=fb[(size_t)i0.y*B_];
        xg[ 2]=fb[(size_t)i0.z*B_]; xg[ 3]=fb[(size_t)i0.w*B_];
        xg[ 4]=fb[(size_t)i1.x*B_]; xg[ 5]=fb[(size_t)i1.y*B_];
        xg[ 6]=fb[(size_t)i1.z*B_]; xg[ 7]=fb[(size_t)i1.w*B_];
        xg[ 8]=fb[(size_t)i2.x*B_]; xg[ 9]=fb[(size_t)i2.y*B_];
        xg[10]=fb[(size_t)i2.z*B_]; xg[11]=fb[(size_t)i2.w*B_];
        xg[12]=fb[(size_t)i3.x*B_]; xg[13]=fb[(size_t)i3.y*B_];
        xg[14]=fb[(size_t)i3.z*B_]; xg[15]=fb[(size_t)i3.w*B_];

        // layer 1: u1 = W1'·xg + b1'  (pairs over output w)
        v2f a0 = P2[64], a1 = P2[65], a2 = P2[66], a3 = P2[67];
        #pragma unroll
        for (int k = 0; k < K_; ++k) {
            float xk = xg[k];
            a0 += P2[4*k+0] * xk;
            a1 += P2[4*k+1] * xk;
            a2 += P2[4*k+2] * xk;
            a3 += P2[4*k+3] * xk;
        }
        float q[W_];
        q[0]=selu_u(a0.x); q[1]=selu_u(a0.y); q[2]=selu_u(a1.x); q[3]=selu_u(a1.y);
        q[4]=selu_u(a2.x); q[5]=selu_u(a2.y); q[6]=selu_u(a3.x); q[7]=selu_u(a3.y);

        // mid layers: u = Wm'·q + bm'  (pairs over output v)
        #pragma unroll
        for (int d = 0; d < D_; ++d) {
            v2f m0 = P2[132+4*d+0], m1 = P2[132+4*d+1],
                m2 = P2[132+4*d+2], m3 = P2[132+4*d+3];
            #pragma unroll
            for (int w = 0; w < W_; ++w) {
                float qw = q[w];
                m0 += P2[68+32*d+4*w+0] * qw;
                m1 += P2[68+32*d+4*w+1] * qw;
                m2 += P2[68+32*d+4*w+2] * qw;
                m3 += P2[68+32*d+4*w+3] * qw;
            }
            q[0]=selu_u(m0.x); q[1]=selu_u(m0.y); q[2]=selu_u(m1.x); q[3]=selu_u(m1.y);
            q[4]=selu_u(m2.x); q[5]=selu_u(m2.y); q[6]=selu_u(m3.x); q[7]=selu_u(m3.y);
        }

        // final dot: out = Wf'·q + bf
        float acc = P[288];
        #pragma unroll
        for (int w = 0; w < W_; ++w) acc = fmaf(q[w], P[280+w], acc);
        res[gi] = acc;
    }

    // coalesced 8B store: (b*20000 + g0) even
    *(float2*)(out + (size_t)b * G_ + g0) = make_float2(res[0], res[1]);
}

// ---------- fallback (no workspace): round-2 path ----------
#define FGPB 4
__device__ __forceinline__ float selu_f(float x) {
    const float scale = 1.0507009873554805f;
    const float sa    = 1.7580993408473766f;
    float e   = __expf(x);
    float neg = fmaf(sa, e, -sa);
    return x > 0.0f ? scale * x : neg;
}
template<bool TRANSPOSED>
__global__ __launch_bounds__(256) void decoder_kernel(
    const float* __restrict__ featsrc, const int* __restrict__ tf_idx,
    const float* __restrict__ W1, const float* __restrict__ b1,
    const float* __restrict__ Wm, const float* __restrict__ bm,
    const float* __restrict__ Wf, const float* __restrict__ bf,
    float* __restrict__ out)
{
    const int b  = threadIdx.x;
    const int g0 = blockIdx.x * FGPB;
    float res[FGPB];
    #pragma unroll
    for (int gi = 0; gi < FGPB; ++gi) {
        const int g = g0 + gi;
        float xg[K_];
        #pragma unroll
        for (int k = 0; k < K_; ++k) {
            int t = tf_idx[g * K_ + k];
            xg[k] = TRANSPOSED ? featsrc[t * B_ + b] : featsrc[b * T_ + t];
        }
        float h[W_];
        #pragma unroll
        for (int w = 0; w < W_; ++w) {
            float acc = b1[g * W_ + w];
            #pragma unroll
            for (int k = 0; k < K_; ++k)
                acc = fmaf(xg[k], W1[(g * W_ + w) * K_ + k], acc);
            h[w] = selu_f(acc);
        }
        #pragma unroll
        for (int d = 0; d < D_; ++d) {
            const float* wmd = Wm + ((size_t)d * G_ + g) * (W_ * W_);
            const float* bmd = bm + ((size_t)d * G_ + g) * W_;
            float h2[W_];
            #pragma unroll
            for (int v = 0; v < W_; ++v) {
                float acc = bmd[v];
                #pragma unroll
                for (int w = 0; w < W_; ++w)
                    acc = fmaf(h[w], wmd[v * W_ + w], acc);
                h2[v] = selu_f(acc);
            }
            #pragma unroll
            for (int w = 0; w < W_; ++w) h[w] = h2[w];
        }
        float acc = bf[g];
        #pragma unroll
        for (int w = 0; w < W_; ++w)
            acc = fmaf(h[w], Wf[g * W_ + w], acc);
        res[gi] = acc;
    }
    float4* o = (float4*)(out + (size_t)b * G_ + g0);
    o[0] = make_float4(res[0], res[1], res[2], res[3]);
}

extern "C" void kernel_launch(void* const* d_in, const int* in_sizes, int n_in,
                              void* d_out, int out_size, void* d_ws, size_t ws_size,
                              hipStream_t stream) {
    const float* feat   = (const float*)d_in[0];
    const int*   tf_idx = (const int*)  d_in[1];
    const float* W1     = (const float*)d_in[2];
    const float* b1     = (const float*)d_in[3];
    const float* Wm     = (const float*)d_in[4];
    const float* bm     = (const float*)d_in[5];
    const float* Wf     = (const float*)d_in[6];
    const float* bf     = (const float*)d_in[7];
    float* out = (float*)d_out;

    const size_t featT_b = (size_t)T_ * B_ * sizeof(float);        // 1.536 MB
    const size_t pack_b  = (size_t)G_ * PSTRIDE * sizeof(float);   // 23.36 MB

    if (ws_size >= featT_b + pack_b) {
        float* featT = (float*)d_ws;
        float* packp = (float*)((char*)d_ws + featT_b);

        dim3 tgrid((T_ + 31) / 32, (B_ + 31) / 32);
        hipLaunchKernelGGL(transpose_feat, tgrid, dim3(32, 8), 0, stream, feat, featT);

        long np = (long)G_ * PSTRIDE;
        hipLaunchKernelGGL(pack_weights, dim3((np + 255) / 256), dim3(256), 0,
                           stream, W1, b1, Wm, bm, Wf, bf, packp);

        hipLaunchKernelGGL(decoder_packed, dim3(G_ / GPB), dim3(B_), 0,
                           stream, featT, tf_idx, packp, out);
    } else if (ws_size >= featT_b) {
        float* featT = (float*)d_ws;
        dim3 tgrid((T_ + 31) / 32, (B_ + 31) / 32);
        hipLaunchKernelGGL(transpose_feat, tgrid, dim3(32, 8), 0, stream, feat, featT);
        hipLaunchKernelGGL((decoder_kernel<true>), dim3(G_ / FGPB), dim3(B_), 0,
                           stream, featT, tf_idx, W1, b1, Wm, bm, Wf, bf, out);
    } else {
        hipLaunchKernelGGL((decoder_kernel<false>), dim3(G_ / FGPB), dim3(B_), 0,
                           stream, feat, tf_idx, W1, b1, Wm, bm, Wf, bf, out);
    }
}

// Round 5
// 90.352 us; speedup vs baseline: 1.1600x; 1.0499x over previous
//
#include <hip/hip_runtime.h>

#define G_ 20000
#define W_ 8
#define K_ 16
#define T_ 1500
#define B_ 256
#define D_ 2
#define GPB 2        // groups per block
#define BPT 2        // batch rows per thread (consecutive -> float2 gathers)
#define TPB 128      // threads per block = B_/BPT; 2 waves
#define PSTRIDE 308  // floats per packed group record (1232 B, 16B-aligned)

typedef float v2f __attribute__((ext_vector_type(2)));

// ---------- prep kernels ----------

// feat (B,T) -> featT (T,B): gathers in main kernel become lane-coalesced.
__global__ void transpose_feat(const float* __restrict__ feat,
                               float* __restrict__ featT) {
    __shared__ float tile[32][33];
    int t0 = blockIdx.x * 32;
    int b0 = blockIdx.y * 32;
    int tx = threadIdx.x, ty = threadIdx.y;  // block (32,8)
    #pragma unroll
    for (int i = 0; i < 32; i += 8) {
        int bb = b0 + ty + i, tt = t0 + tx;
        if (bb < B_ && tt < T_) tile[ty + i][tx] = feat[bb * T_ + tt];
    }
    __syncthreads();
    #pragma unroll
    for (int i = 0; i < 32; i += 8) {
        int tt = t0 + ty + i, bb = b0 + tx;
        if (tt < T_ && bb < B_) featT[tt * B_ + bb] = tile[tx][ty + i];
    }
}

// One contiguous record per group; SELU constants folded; indices first
// (premultiplied by B) so the gather s_loads issue earliest.
// Layout (floats):
//   [0,16)    tf_idx*B_ (int bits)
//   [16,144)  W1t[k][w]  * log2e
//   [144,152) b1         * log2e
//   [152,280) Wmt[d][w][v] * scale*log2e
//   [280,296) bm[d][v]   * log2e
//   [296,304) Wf         * scale
//   [304]     bf
//   [305,308) pad
__global__ void pack_weights(const int*   __restrict__ tf_idx,
                             const float* __restrict__ W1,
                             const float* __restrict__ b1,
                             const float* __restrict__ Wm,
                             const float* __restrict__ bm,
                             const float* __restrict__ Wf,
                             const float* __restrict__ bf,
                             float* __restrict__ pack) {
    long i = (long)blockIdx.x * blockDim.x + threadIdx.x;
    if (i >= (long)G_ * PSTRIDE) return;
    int g = (int)(i / PSTRIDE);
    int j = (int)(i - (long)g * PSTRIDE);
    const float LOG2E = 1.44269504088896340736f;
    const float SCALE = 1.0507009873554805f;
    float v;
    if (j < 16) {
        int t = tf_idx[g * K_ + j];
        v = __int_as_float(t * B_);
    } else if (j < 144) {
        int r = j - 16, k = r >> 3, w = r & 7;
        v = LOG2E * W1[((long)g * W_ + w) * K_ + k];
    } else if (j < 152) {
        v = LOG2E * b1[g * W_ + (j - 144)];
    } else if (j < 280) {
        int r = j - 152, d = r >> 6, w = (r >> 3) & 7, vv = r & 7;
        v = SCALE * LOG2E * Wm[(((long)d * G_ + g) * W_ + vv) * W_ + w];
    } else if (j < 296) {
        int r = j - 280, d = r >> 3, vv = r & 7;
        v = LOG2E * bm[((long)d * G_ + g) * W_ + vv];
    } else if (j < 304) {
        v = SCALE * Wf[g * W_ + (j - 296)];
    } else if (j == 304) {
        v = bf[g];
    } else {
        v = 0.0f;
    }
    pack[i] = v;
}

// ---------- main kernel ----------

// input u = log2e * z ; returns selu(z)/scale (scale folded into consumer)
__device__ __forceinline__ float selu_u(float u) {
    const float ALPHA = 1.6732632423543772f;
    const float LN2   = 0.6931471805599453f;
    float e   = __builtin_amdgcn_exp2f(u);      // single v_exp_f32
    float neg = fmaf(ALPHA, e, -ALPHA);
    return u > 0.0f ? u * LN2 : neg;
}

// 128 threads (2 waves), thread owns batch rows {2*tid, 2*tid+1} for GPB
// consecutive groups. Weight record uniform -> s_load broadcast; per-wave
// s_load cost amortized over 2x compute vs round 4.
__global__ __launch_bounds__(TPB, 6) void decoder_packed2(
    const float* __restrict__ featT,   // (T,B)
    const float* __restrict__ pack,    // (G,PSTRIDE)
    float* __restrict__ out)           // (B,G)
{
    const int tid = threadIdx.x;
    const int b0  = BPT * tid;
    const int g0  = blockIdx.x * GPB;
    const float* fb = featT + b0;
    float res[BPT][GPB];

    #pragma unroll
    for (int gi = 0; gi < GPB; ++gi) {
        const int g = g0 + gi;
        const float* P    = pack + (long)g * PSTRIDE;
        const int*   idxp = (const int*)P;            // [0,16): t*B_
        const v2f*   Pw1  = (const v2f*)(P + 16);     // W1t pairs
        const v2f*   Pb1  = (const v2f*)(P + 144);
        const v2f*   Pwm  = (const v2f*)(P + 152);
        const v2f*   Pbm  = (const v2f*)(P + 280);

        // coalesced float2 gathers: both batch rows in one dwordx2
        float2 xg[K_];
        #pragma unroll
        for (int k = 0; k < K_; ++k)
            xg[k] = *(const float2*)(fb + idxp[k]);

        // layer 1: pk-acc over output pairs, one acc set per batch row
        v2f a0[4], a1[4];
        #pragma unroll
        for (int j = 0; j < 4; ++j) { a0[j] = Pb1[j]; a1[j] = Pb1[j]; }
        #pragma unroll
        for (int k = 0; k < K_; ++k) {
            float x0 = xg[k].x, x1 = xg[k].y;
            #pragma unroll
            for (int j = 0; j < 4; ++j) {
                v2f wv = Pw1[4 * k + j];
                a0[j] += wv * x0;
                a1[j] += wv * x1;
            }
        }
        float q0[W_], q1[W_];
        #pragma unroll
        for (int j = 0; j < 4; ++j) {
            q0[2*j] = selu_u(a0[j].x); q0[2*j+1] = selu_u(a0[j].y);
            q1[2*j] = selu_u(a1[j].x); q1[2*j+1] = selu_u(a1[j].y);
        }

        // mid layers
        #pragma unroll
        for (int d = 0; d < D_; ++d) {
            v2f m0[4], m1[4];
            #pragma unroll
            for (int j = 0; j < 4; ++j) { m0[j] = Pbm[4*d+j]; m1[j] = Pbm[4*d+j]; }
            #pragma unroll
            for (int w = 0; w < W_; ++w) {
                float h0 = q0[w], h1 = q1[w];
                #pragma unroll
                for (int j = 0; j < 4; ++j) {
                    v2f wv = Pwm[(d * W_ + w) * 4 + j];
                    m0[j] += wv * h0;
                    m1[j] += wv * h1;
                }
            }
            #pragma unroll
            for (int j = 0; j < 4; ++j) {
                q0[2*j] = selu_u(m0[j].x); q0[2*j+1] = selu_u(m0[j].y);
                q1[2*j] = selu_u(m1[j].x); q1[2*j+1] = selu_u(m1[j].y);
            }
        }

        // final dot
        float acc0 = P[304], acc1 = P[304];
        #pragma unroll
        for (int w = 0; w < W_; ++w) {
            float wf = P[296 + w];
            acc0 = fmaf(q0[w], wf, acc0);
            acc1 = fmaf(q1[w], wf, acc1);
        }
        res[0][gi] = acc0;
        res[1][gi] = acc1;
    }

    // 8B stores per batch row ((b*20000+g0) even -> aligned)
    #pragma unroll
    for (int bb = 0; bb < BPT; ++bb)
        *(float2*)(out + (size_t)(b0 + bb) * G_ + g0) =
            make_float2(res[bb][0], res[bb][1]);
}

// ---------- fallbacks (small workspace) ----------
#define FGPB 4
__device__ __forceinline__ float selu_f(float x) {
    const float scale = 1.0507009873554805f;
    const float sa    = 1.7580993408473766f;
    float e   = __expf(x);
    float neg = fmaf(sa, e, -sa);
    return x > 0.0f ? scale * x : neg;
}
template<bool TRANSPOSED>
__global__ __launch_bounds__(256) void decoder_kernel(
    const float* __restrict__ featsrc, const int* __restrict__ tf_idx,
    const float* __restrict__ W1, const float* __restrict__ b1,
    const float* __restrict__ Wm, const float* __restrict__ bm,
    const float* __restrict__ Wf, const float* __restrict__ bf,
    float* __restrict__ out)
{
    const int b  = threadIdx.x;
    const int g0 = blockIdx.x * FGPB;
    float res[FGPB];
    #pragma unroll
    for (int gi = 0; gi < FGPB; ++gi) {
        const int g = g0 + gi;
        float xg[K_];
        #pragma unroll
        for (int k = 0; k < K_; ++k) {
            int t = tf_idx[g * K_ + k];
            xg[k] = TRANSPOSED ? featsrc[t * B_ + b] : featsrc[b * T_ + t];
        }
        float h[W_];
        #pragma unroll
        for (int w = 0; w < W_; ++w) {
            float acc = b1[g * W_ + w];
            #pragma unroll
            for (int k = 0; k < K_; ++k)
                acc = fmaf(xg[k], W1[(g * W_ + w) * K_ + k], acc);
            h[w] = selu_f(acc);
        }
        #pragma unroll
        for (int d = 0; d < D_; ++d) {
            const float* wmd = Wm + ((size_t)d * G_ + g) * (W_ * W_);
            const float* bmd = bm + ((size_t)d * G_ + g) * W_;
            float h2[W_];
            #pragma unroll
            for (int v = 0; v < W_; ++v) {
                float acc = bmd[v];
                #pragma unroll
                for (int w = 0; w < W_; ++w)
                    acc = fmaf(h[w], wmd[v * W_ + w], acc);
                h2[v] = selu_f(acc);
            }
            #pragma unroll
            for (int w = 0; w < W_; ++w) h[w] = h2[w];
        }
        float acc = bf[g];
        #pragma unroll
        for (int w = 0; w < W_; ++w)
            acc = fmaf(h[w], Wf[g * W_ + w], acc);
        res[gi] = acc;
    }
    float4* o = (float4*)(out + (size_t)b * G_ + g0);
    o[0] = make_float4(res[0], res[1], res[2], res[3]);
}

extern "C" void kernel_launch(void* const* d_in, const int* in_sizes, int n_in,
                              void* d_out, int out_size, void* d_ws, size_t ws_size,
                              hipStream_t stream) {
    const float* feat   = (const float*)d_in[0];
    const int*   tf_idx = (const int*)  d_in[1];
    const float* W1     = (const float*)d_in[2];
    const float* b1     = (const float*)d_in[3];
    const float* Wm     = (const float*)d_in[4];
    const float* bm     = (const float*)d_in[5];
    const float* Wf     = (const float*)d_in[6];
    const float* bf     = (const float*)d_in[7];
    float* out = (float*)d_out;

    const size_t featT_b = (size_t)T_ * B_ * sizeof(float);        // 1.536 MB
    const size_t pack_b  = (size_t)G_ * PSTRIDE * sizeof(float);   // 24.64 MB

    if (ws_size >= featT_b + pack_b) {
        float* featT = (float*)d_ws;
        float* packp = (float*)((char*)d_ws + featT_b);

        dim3 tgrid((T_ + 31) / 32, (B_ + 31) / 32);
        hipLaunchKernelGGL(transpose_feat, tgrid, dim3(32, 8), 0, stream, feat, featT);

        long np = (long)G_ * PSTRIDE;
        hipLaunchKernelGGL(pack_weights, dim3((np + 255) / 256), dim3(256), 0,
                           stream, tf_idx, W1, b1, Wm, bm, Wf, bf, packp);

        hipLaunchKernelGGL(decoder_packed2, dim3(G_ / GPB), dim3(TPB), 0,
                           stream, featT, packp, out);
    } else if (ws_size >= featT_b) {
        float* featT = (float*)d_ws;
        dim3 tgrid((T_ + 31) / 32, (B_ + 31) / 32);
        hipLaunchKernelGGL(transpose_feat, tgrid, dim3(32, 8), 0, stream, feat, featT);
        hipLaunchKernelGGL((decoder_kernel<true>), dim3(G_ / FGPB), dim3(B_), 0,
                           stream, featT, tf_idx, W1, b1, Wm, bm, Wf, bf, out);
    } else {
        hipLaunchKernelGGL((decoder_kernel<false>), dim3(G_ / FGPB), dim3(B_), 0,
                           stream, feat, tf_idx, W1, b1, Wm, bm, Wf, bf, out);
    }
}